// Round 1
// baseline (1428.592 us; speedup 1.0000x reference)
//
#include <hip/hip_runtime.h>
#include <cstdint>

#define N_ANCH 16384
#define NBLK 256      // number of 64-box blocks
#define CAP 64        // max cross-block suppression targets stored per row
#define PROP 2000

typedef unsigned long long u64;
typedef unsigned int u32;
typedef unsigned short u16;

// ---------------- Kernel A: decode boxes + build sort keys ----------------
__global__ __launch_bounds__(256) void decode_kernel(
    const float* __restrict__ cls, const float* __restrict__ bbox,
    const float* __restrict__ anch, float4* __restrict__ boxes_u,
    u64* __restrict__ keys)
{
  int i = blockIdx.x * 256 + threadIdx.x;
  if (i >= N_ANCH) return;
  float s = cls[i];
  float4 bb = ((const float4*)bbox)[i];
  float4 aa = ((const float4*)anch)[i];
  float d0 = s * bb.x, d1 = s * bb.y, d2 = s * bb.z, d3 = s * bb.w;
  float wa = aa.z - aa.x;
  float ha = aa.w - aa.y;
  float cx = aa.x + 0.5f * wa + d0 * wa;
  float cy = aa.y + 0.5f * ha + d1 * ha;
  float w = wa * expf(d2);
  float h = ha * expf(d3);
  float x1 = fmaxf(cx - 0.5f * w, 0.f);
  float y1 = fmaxf(cy - 0.5f * h, 0.f);
  float x2 = fminf(cx + 0.5f * w, 1023.f);
  float y2 = fminf(cy + 0.5f * h, 1023.f);
  boxes_u[i] = make_float4(x1, y1, x2, y2);
  // scores are uniform [0,1): nonnegative -> float bits monotone.
  // key ascending == (score desc, idx asc) == stable argsort(-scores)
  u32 sb = __float_as_uint(s);
  keys[i] = ((u64)(sb ^ 0xFFFFFFFFu) << 32) | (u32)i;
}

// ---------------- Kernel B: enumeration sort (rank = #keys smaller) -------
// grid 256 x 256 threads; 64 rows/block, 4 threads per row.
__global__ __launch_bounds__(256) void rank_kernel(
    const u64* __restrict__ keys, const float4* __restrict__ boxes_u,
    float4* __restrict__ bS, float* __restrict__ areaS)
{
  __shared__ u64 kt[256];
  int tid = threadIdx.x;
  int row = blockIdx.x * 64 + (tid >> 2);
  int sub = tid & 3;
  u64 ki = keys[row];
  int cnt = 0;
  for (int t = 0; t < 64; ++t) {
    __syncthreads();
    kt[tid] = keys[t * 256 + tid];
    __syncthreads();
#pragma unroll
    for (int q = 0; q < 64; ++q) {
      cnt += (kt[sub + 4 * q] < ki) ? 1 : 0;
    }
  }
  cnt += __shfl_xor(cnt, 1);
  cnt += __shfl_xor(cnt, 2);
  if (sub == 0) {
    int idx = (int)(ki & 0xFFFFFFFFull);
    float4 b = boxes_u[idx];
    bS[cnt] = b;
    areaS[cnt] = (b.z - b.x) * (b.w - b.y);
  }
}

// ---------------- Kernel C: sparse suppression pairs ----------------------
// grid 256 blocks (one per 64-row block) x 256 threads (4 per row).
__global__ __launch_bounds__(256) void mask_kernel(
    const float4* __restrict__ bS, const float* __restrict__ areaS,
    u32* __restrict__ counts, u64* __restrict__ intra,
    u16* __restrict__ entries)
{
  __shared__ u32 cntL[64];
  __shared__ u64 intraL[64];
  int tid = threadIdx.x;
  int rb = blockIdx.x;
  int rl = tid >> 2, sub = tid & 3;
  int i = rb * 64 + rl;
  if (tid < 64) { cntL[tid] = 0; intraL[tid] = 0ull; }
  __syncthreads();
  float4 bi = bS[i];
  float ai = areaS[i];
  int blkEnd = (rb + 1) * 64;
  for (int j = i + 1 + sub; j < N_ANCH; j += 4) {
    float4 bj = bS[j];
    float dx = fminf(bi.z, bj.z) - fmaxf(bi.x, bj.x);
    if (dx <= 0.f) continue;
    float dy = fminf(bi.w, bj.w) - fmaxf(bi.y, bj.y);
    if (dy <= 0.f) continue;
    float inter = dx * dy;
    float un = ai + areaS[j] - inter;
    float um = fmaxf(un, 1e-8f);
    float thr = 0.7f * um;
    bool sup;
    if (inter > thr * 1.00002f) sup = true;          // clearly above
    else if (inter < thr * 0.99998f) sup = false;    // clearly below
    else sup = ((inter / um) > 0.7f);                // exact IEEE fallback
    if (sup) {
      if (j < blkEnd) {
        atomicOr(&intraL[rl], 1ull << (j & 63));
      } else {
        u32 p = atomicAdd(&cntL[rl], 1u);
        if (p < CAP) entries[(u32)i * CAP + p] = (u16)j;
      }
    }
  }
  __syncthreads();
  if (tid < 64) {
    u32 c = cntL[tid];
    counts[rb * 64 + tid] = (c < (u32)CAP) ? c : (u32)CAP;
    intra[rb * 64 + tid] = intraL[tid];
  }
}

// ---------------- Kernel D: sequential greedy resolve + output ------------
// single wave; walks 64-box blocks in order, early-exits at 2000 kept.
__global__ __launch_bounds__(64) void resolve_kernel(
    const u32* __restrict__ counts, const u64* __restrict__ intra,
    const u16* __restrict__ entries, const float4* __restrict__ bS,
    float4* __restrict__ out)
{
  __shared__ u64 removedL[NBLK];
  int tid = threadIdx.x;
  for (int t = tid; t < NBLK; t += 64) removedL[t] = 0ull;
  __syncthreads();
  int total = 0;
  // prefetch block 0
  u32 c_cur = counts[tid];
  u64 iv_cur = intra[tid];
  float4 b_cur = bS[tid];
  for (int rb = 0; rb < NBLK; ++rb) {
    u32 c_nxt = 0; u64 iv_nxt = 0; float4 b_nxt = make_float4(0, 0, 0, 0);
    if (rb + 1 < NBLK) {
      int ni = (rb + 1) * 64 + tid;
      c_nxt = counts[ni];
      iv_nxt = intra[ni];
      b_nxt = bS[ni];
    }
    u64 r = removedL[rb];
    u64 cand = ~r;
    u64 iw = __ballot(iv_cur != 0ull);
    if (cand & iw) {
      // rare: intra-block suppression chain; resolve serially (uniform)
      u64 rr = r;
      for (int k = 0; k < 64; ++k) {
        u64 mk = __shfl(iv_cur, k, 64);
        if (!((rr >> k) & 1ull)) rr |= mk;
      }
      cand = ~rr;
    }
    u64 kw = cand;
    bool keep = (kw >> tid) & 1ull;
    int rank = total + __popcll(kw & ((1ull << tid) - 1ull));
    if (keep && rank < PROP) out[rank] = b_cur;
    total += __popcll(kw);
    if (total >= PROP) break;  // later blocks can't affect earlier output
    if (keep && c_cur > 0) {
      const u16* e = entries + (u32)(rb * 64 + tid) * CAP;
      for (u32 q = 0; q < c_cur; ++q) {
        int j = e[q];
        atomicOr(&removedL[j >> 6], 1ull << (j & 63));
      }
    }
    __syncthreads();
    c_cur = c_nxt; iv_cur = iv_nxt; b_cur = b_nxt;
  }
  int tk = (total < PROP) ? total : PROP;
  for (int s = tk + tid; s < PROP; s += 64)
    out[s] = make_float4(0.f, 0.f, 0.f, 0.f);
}

// --------------------------------------------------------------------------
extern "C" void kernel_launch(void* const* d_in, const int* in_sizes, int n_in,
                              void* d_out, int out_size, void* d_ws, size_t ws_size,
                              hipStream_t stream)
{
  const float* cls  = (const float*)d_in[0];   // rpn_class  (16384,1)
  const float* bbox = (const float*)d_in[1];   // rpn_bbox   (16384,4)
  const float* anch = (const float*)d_in[2];   // anchors    (16384,4)
  // d_in[3] = image (only shape used by reference)

  uint8_t* w = (uint8_t*)d_ws;
  float4* boxes_u = (float4*)(w);                    // 256 KB
  u64*    keys    = (u64*)(w + (256 << 10));         // 128 KB
  float4* bS      = (float4*)(w + (384 << 10));      // 256 KB
  float*  areaS   = (float*)(w + (640 << 10));       //  64 KB
  u32*    counts  = (u32*)(w + (704 << 10));         //  64 KB
  u64*    intra   = (u64*)(w + (768 << 10));         // 128 KB
  u16*    entries = (u16*)(w + (896 << 10));         //   2 MB
  float4* out     = (float4*)d_out;                  // 2000 x float4

  decode_kernel<<<64, 256, 0, stream>>>(cls, bbox, anch, boxes_u, keys);
  rank_kernel<<<256, 256, 0, stream>>>(keys, boxes_u, bS, areaS);
  mask_kernel<<<256, 256, 0, stream>>>(bS, areaS, counts, intra, entries);
  resolve_kernel<<<1, 64, 0, stream>>>(counts, intra, entries, bS, out);
}

// Round 2
// 248.937 us; speedup vs baseline: 5.7388x; 5.7388x over previous
//
#include <hip/hip_runtime.h>
#include <cstdint>

#define N_ANCH 16384
#define NBLK 256      // number of 64-box blocks
#define CAP 64        // max cross-block suppression targets stored per row
#define PROP 2000
#define TILE 256
#define NT (N_ANCH / TILE)            // 64 row/col tiles
#define NPAIRS (NT * (NT + 1) / 2)    // 2080 tile-pair blocks

typedef unsigned long long u64;
typedef unsigned int u32;
typedef unsigned short u16;

// ---------------- Kernel A: decode boxes + build sort keys ----------------
__global__ __launch_bounds__(256) void decode_kernel(
    const float* __restrict__ cls, const float* __restrict__ bbox,
    const float* __restrict__ anch, float4* __restrict__ boxes_u,
    u64* __restrict__ keys)
{
  int i = blockIdx.x * 256 + threadIdx.x;
  if (i >= N_ANCH) return;
  float s = cls[i];
  float4 bb = ((const float4*)bbox)[i];
  float4 aa = ((const float4*)anch)[i];
  float d0 = s * bb.x, d1 = s * bb.y, d2 = s * bb.z, d3 = s * bb.w;
  float wa = aa.z - aa.x;
  float ha = aa.w - aa.y;
  float cx = aa.x + 0.5f * wa + d0 * wa;
  float cy = aa.y + 0.5f * ha + d1 * ha;
  float w = wa * expf(d2);
  float h = ha * expf(d3);
  float x1 = fmaxf(cx - 0.5f * w, 0.f);
  float y1 = fmaxf(cy - 0.5f * h, 0.f);
  float x2 = fminf(cx + 0.5f * w, 1023.f);
  float y2 = fminf(cy + 0.5f * h, 1023.f);
  boxes_u[i] = make_float4(x1, y1, x2, y2);
  u32 sb = __float_as_uint(s);
  keys[i] = ((u64)(sb ^ 0xFFFFFFFFu) << 32) | (u32)i;
}

// ---------------- Kernel A2: zero counts/intra ----------------------------
__global__ __launch_bounds__(256) void init_kernel(
    u32* __restrict__ counts, u64* __restrict__ intra)
{
  int i = blockIdx.x * 256 + threadIdx.x;
  counts[i] = 0u;
  intra[i] = 0ull;
}

// ---------------- Kernel B: enumeration sort (rank = #keys smaller) -------
__global__ __launch_bounds__(256) void rank_kernel(
    const u64* __restrict__ keys, const float4* __restrict__ boxes_u,
    float4* __restrict__ bS, float* __restrict__ areaS)
{
  __shared__ u64 kt[256];
  int tid = threadIdx.x;
  int row = blockIdx.x * 64 + (tid >> 2);
  int sub = tid & 3;
  u64 ki = keys[row];
  int cnt = 0;
  for (int t = 0; t < 64; ++t) {
    __syncthreads();
    kt[tid] = keys[t * 256 + tid];
    __syncthreads();
#pragma unroll
    for (int q = 0; q < 64; ++q) {
      cnt += (kt[sub + 4 * q] < ki) ? 1 : 0;
    }
  }
  cnt += __shfl_xor(cnt, 1);
  cnt += __shfl_xor(cnt, 2);
  if (sub == 0) {
    int idx = (int)(ki & 0xFFFFFFFFull);
    float4 b = boxes_u[idx];
    bS[cnt] = b;
    areaS[cnt] = (b.z - b.x) * (b.w - b.y);
  }
}

// ---------------- Kernel C: sparse suppression pairs (tile-pair grid) -----
// 2080 blocks, one per (ta<=tb) 256x256 tile pair; j-tile staged in LDS.
__global__ __launch_bounds__(256) void mask_kernel(
    const float4* __restrict__ bS, const float* __restrict__ areaS,
    u32* __restrict__ counts, u64* __restrict__ intra,
    u16* __restrict__ entries)
{
  __shared__ float4 bT[TILE];
  __shared__ float aT[TILE];
  int tid = threadIdx.x;
  // map linear block id -> triangular (ta, tb)
  int rem = blockIdx.x;
  int ta = 0, rowlen = NT;
  while (rem >= rowlen) { rem -= rowlen; ++ta; --rowlen; }
  int tb = ta + rem;

  int i = ta * TILE + tid;
  float4 bi = bS[i];
  float ai = areaS[i];
  int jbase = tb * TILE;
  bT[tid] = bS[jbase + tid];
  aT[tid] = areaS[jbase + tid];
  __syncthreads();

  u64 myIntra = 0ull;
  int iblk = i >> 6;
#pragma unroll 4
  for (int q = 0; q < TILE; ++q) {
    int j = jbase + q;
    if (j <= i) continue;
    float4 bj = bT[q];
    float dx = fminf(bi.z, bj.z) - fmaxf(bi.x, bj.x);
    float dy = fminf(bi.w, bj.w) - fmaxf(bi.y, bj.y);
    if (dx <= 0.f || dy <= 0.f) continue;
    float inter = dx * dy;
    float un = ai + aT[q] - inter;
    float um = fmaxf(un, 1e-8f);
    float thr = 0.7f * um;
    bool sup;
    if (inter > thr * 1.00002f) sup = true;          // clearly above
    else if (inter < thr * 0.99998f) sup = false;    // clearly below
    else sup = ((inter / um) > 0.7f);                // exact IEEE fallback
    if (sup) {
      if ((j >> 6) == iblk) {
        myIntra |= 1ull << (j & 63);
      } else {
        u32 p = atomicAdd(&counts[i], 1u);
        if (p < CAP) entries[(u32)i * CAP + p] = (u16)j;
      }
    }
  }
  if (myIntra) atomicOr(&intra[i], myIntra);
}

// ---------------- Kernel D: sequential greedy resolve + output ------------
__global__ __launch_bounds__(64) void resolve_kernel(
    const u32* __restrict__ counts, const u64* __restrict__ intra,
    const u16* __restrict__ entries, const float4* __restrict__ bS,
    float4* __restrict__ out)
{
  __shared__ u64 removedL[NBLK];
  int tid = threadIdx.x;
  for (int t = tid; t < NBLK; t += 64) removedL[t] = 0ull;
  __syncthreads();
  int total = 0;
  u32 c_cur = counts[tid]; c_cur = (c_cur < (u32)CAP) ? c_cur : (u32)CAP;
  u64 iv_cur = intra[tid];
  float4 b_cur = bS[tid];
  for (int rb = 0; rb < NBLK; ++rb) {
    u32 c_nxt = 0; u64 iv_nxt = 0; float4 b_nxt = make_float4(0, 0, 0, 0);
    if (rb + 1 < NBLK) {
      int ni = (rb + 1) * 64 + tid;
      c_nxt = counts[ni]; c_nxt = (c_nxt < (u32)CAP) ? c_nxt : (u32)CAP;
      iv_nxt = intra[ni];
      b_nxt = bS[ni];
    }
    u64 r = removedL[rb];
    u64 cand = ~r;
    u64 iw = __ballot(iv_cur != 0ull);
    if (cand & iw) {
      u64 rr = r;
      for (int k = 0; k < 64; ++k) {
        u64 mk = __shfl(iv_cur, k, 64);
        if (!((rr >> k) & 1ull)) rr |= mk;
      }
      cand = ~rr;
    }
    u64 kw = cand;
    bool keep = (kw >> tid) & 1ull;
    int rank = total + __popcll(kw & ((1ull << tid) - 1ull));
    if (keep && rank < PROP) out[rank] = b_cur;
    total += __popcll(kw);
    if (total >= PROP) break;
    if (keep && c_cur > 0) {
      const u16* e = entries + (u32)(rb * 64 + tid) * CAP;
      for (u32 q = 0; q < c_cur; ++q) {
        int j = e[q];
        atomicOr(&removedL[j >> 6], 1ull << (j & 63));
      }
    }
    __syncthreads();
    c_cur = c_nxt; iv_cur = iv_nxt; b_cur = b_nxt;
  }
  int tk = (total < PROP) ? total : PROP;
  for (int s = tk + tid; s < PROP; s += 64)
    out[s] = make_float4(0.f, 0.f, 0.f, 0.f);
}

// --------------------------------------------------------------------------
extern "C" void kernel_launch(void* const* d_in, const int* in_sizes, int n_in,
                              void* d_out, int out_size, void* d_ws, size_t ws_size,
                              hipStream_t stream)
{
  const float* cls  = (const float*)d_in[0];   // rpn_class  (16384,1)
  const float* bbox = (const float*)d_in[1];   // rpn_bbox   (16384,4)
  const float* anch = (const float*)d_in[2];   // anchors    (16384,4)

  uint8_t* w = (uint8_t*)d_ws;
  float4* boxes_u = (float4*)(w);                    // 256 KB
  u64*    keys    = (u64*)(w + (256 << 10));         // 128 KB
  float4* bS      = (float4*)(w + (384 << 10));      // 256 KB
  float*  areaS   = (float*)(w + (640 << 10));       //  64 KB
  u32*    counts  = (u32*)(w + (704 << 10));         //  64 KB
  u64*    intra   = (u64*)(w + (768 << 10));         // 128 KB
  u16*    entries = (u16*)(w + (896 << 10));         //   2 MB
  float4* out     = (float4*)d_out;                  // 2000 x float4

  decode_kernel<<<64, 256, 0, stream>>>(cls, bbox, anch, boxes_u, keys);
  init_kernel<<<64, 256, 0, stream>>>(counts, intra);
  rank_kernel<<<256, 256, 0, stream>>>(keys, boxes_u, bS, areaS);
  mask_kernel<<<NPAIRS, 256, 0, stream>>>(bS, areaS, counts, intra, entries);
  resolve_kernel<<<1, 64, 0, stream>>>(counts, intra, entries, bS, out);
}

// Round 3
// 184.123 us; speedup vs baseline: 7.7589x; 1.3520x over previous
//
#include <hip/hip_runtime.h>
#include <cstdint>

#define N_ANCH 16384
#define NBLK 256      // number of 64-box blocks
#define CAP 64        // max cross-block suppression targets stored per row
#define PROP 2000
#define TILE 256
#define NT (N_ANCH / TILE)            // 64 row/col tiles
#define NPAIRS (NT * (NT + 1) / 2)    // 2080 tile-pair blocks
#define RANK_CY 4                     // column chunks for rank kernel

typedef unsigned long long u64;
typedef unsigned int u32;
typedef unsigned short u16;

#define C_HI (0.7f * 1.00002f)
#define C_LO (0.7f * 0.99998f)

// ---------------- Kernel A: decode boxes + build sort keys ----------------
__global__ __launch_bounds__(256) void decode_kernel(
    const float* __restrict__ cls, const float* __restrict__ bbox,
    const float* __restrict__ anch, float4* __restrict__ boxes_u,
    u64* __restrict__ keys)
{
  int i = blockIdx.x * 256 + threadIdx.x;
  if (i >= N_ANCH) return;
  float s = cls[i];
  float4 bb = ((const float4*)bbox)[i];
  float4 aa = ((const float4*)anch)[i];
  float d0 = s * bb.x, d1 = s * bb.y, d2 = s * bb.z, d3 = s * bb.w;
  float wa = aa.z - aa.x;
  float ha = aa.w - aa.y;
  float cx = aa.x + 0.5f * wa + d0 * wa;
  float cy = aa.y + 0.5f * ha + d1 * ha;
  float w = wa * expf(d2);
  float h = ha * expf(d3);
  float x1 = fmaxf(cx - 0.5f * w, 0.f);
  float y1 = fmaxf(cy - 0.5f * h, 0.f);
  float x2 = fminf(cx + 0.5f * w, 1023.f);
  float y2 = fminf(cy + 0.5f * h, 1023.f);
  boxes_u[i] = make_float4(x1, y1, x2, y2);
  u32 sb = __float_as_uint(s);
  keys[i] = ((u64)(sb ^ 0xFFFFFFFFu) << 32) | (u32)i;
}

// ---------------- Kernel A2: zero counts + rank ----------------------------
__global__ __launch_bounds__(256) void init_kernel(
    u32* __restrict__ counts, u32* __restrict__ rankArr)
{
  int i = blockIdx.x * 256 + threadIdx.x;
  counts[i] = 0u;
  rankArr[i] = 0u;
}

// ---------------- Kernel B: partial rank (column-split enumeration) -------
// grid (256, 4): block (rb, cy) counts keys-smaller within column chunk cy
// for the 64 rows of row-block rb. 4 threads per row.
__global__ __launch_bounds__(256) void rank_kernel(
    const u64* __restrict__ keys, u32* __restrict__ rankArr)
{
  __shared__ u64 kt[256];
  int tid = threadIdx.x;
  int row = blockIdx.x * 64 + (tid >> 2);
  int sub = tid & 3;
  int cbase = blockIdx.y * (N_ANCH / RANK_CY);
  u64 ki = keys[row];
  int cnt = 0;
  for (int t = 0; t < N_ANCH / RANK_CY / 256; ++t) {  // 16 rounds
    __syncthreads();
    kt[tid] = keys[cbase + t * 256 + tid];
    __syncthreads();
#pragma unroll
    for (int q = 0; q < 64; ++q)
      cnt += (kt[sub + 4 * q] < ki) ? 1 : 0;
  }
  cnt += __shfl_xor(cnt, 1);
  cnt += __shfl_xor(cnt, 2);
  if (sub == 0) atomicAdd(&rankArr[row], (u32)cnt);
}

// ---------------- Kernel B2: scatter boxes into sorted order --------------
__global__ __launch_bounds__(256) void scatter_kernel(
    const u32* __restrict__ rankArr, const float4* __restrict__ boxes_u,
    float4* __restrict__ bS, float* __restrict__ areaS)
{
  int i = blockIdx.x * 256 + threadIdx.x;
  u32 r = rankArr[i];
  float4 b = boxes_u[i];
  bS[r] = b;
  areaS[r] = (b.z - b.x) * (b.w - b.y);
}

// ---------------- Kernel C: sparse suppression pairs (tile-pair grid) -----
// 2080 blocks, one per (ta<=tb) 256x256 tile pair; j-tile staged in LDS.
// Branchless bitmask accumulation over 64-j chunks, rare sparse flush.
__global__ __launch_bounds__(256) void mask_kernel(
    const float4* __restrict__ bS, const float* __restrict__ areaS,
    u32* __restrict__ counts, u64* __restrict__ intra,
    u16* __restrict__ entries)
{
  __shared__ float4 bT[TILE];
  __shared__ float aT[TILE];
  int tid = threadIdx.x;
  // map linear block id -> triangular (ta, tb)
  int rem = blockIdx.x;
  int ta = 0, rowlen = NT;
  while (rem >= rowlen) { rem -= rowlen; ++ta; --rowlen; }
  int tb = ta + rem;

  int i = ta * TILE + tid;
  float4 bi = bS[i];
  float ai = areaS[i];
  int jbase = tb * TILE;
  bT[tid] = bS[jbase + tid];
  aT[tid] = areaS[jbase + tid];
  __syncthreads();

  auto compute_mask = [&](int ch) -> u64 {
    u32 mlo = 0u, mhi = 0u;
    const float4* bp = &bT[ch * 64];
    const float* ap = &aT[ch * 64];
#pragma unroll
    for (int qq = 0; qq < 64; ++qq) {
      float4 bj = bp[qq];
      float aj = ap[qq];
      float dx = fminf(bi.z, bj.z) - fmaxf(bi.x, bj.x);
      float dy = fminf(bi.w, bj.w) - fmaxf(bi.y, bj.y);
      float inter = fmaxf(dx, 0.f) * fmaxf(dy, 0.f);
      float um = fmaxf(ai + aj - inter, 1e-8f);
      bool hi = inter > um * C_HI;
      bool lo = inter > um * C_LO;
      if (hi != lo) hi = (inter / um) > 0.7f;  // rare exact IEEE fallback
      if (qq < 32) mlo |= hi ? (1u << qq) : 0u;
      else         mhi |= hi ? (1u << (qq - 32)) : 0u;
    }
    return ((u64)mhi << 32) | (u64)mlo;
  };

  auto flush = [&](u64 m, int ch) {
    int jb = jbase + ch * 64;
    while (m) {
      int b = __builtin_ctzll(m);
      m &= m - 1;
      u32 p = atomicAdd(&counts[i], 1u);
      if (p < CAP) entries[(u32)i * CAP + p] = (u16)(jb + b);
    }
  };

  if (ta == tb) {
    int wave = tid >> 6, lane = tid & 63;
    // chunk == wave: intra-64-block triangular bits (plain store, one writer)
    u64 m = compute_mask(wave);
    m &= (~1ull) << lane;  // keep bits qq > lane (excludes self)
    intra[i] = m;
    // chunks above the wave: full cross-block
    for (int ch = wave + 1; ch < 4; ++ch) flush(compute_mask(ch), ch);
  } else {
#pragma unroll
    for (int ch = 0; ch < 4; ++ch) flush(compute_mask(ch), ch);
  }
}

// ---------------- Kernel D: sequential greedy resolve + output ------------
__global__ __launch_bounds__(64) void resolve_kernel(
    const u32* __restrict__ counts, const u64* __restrict__ intra,
    const u16* __restrict__ entries, const float4* __restrict__ bS,
    float4* __restrict__ out)
{
  __shared__ u64 removedL[NBLK];
  int tid = threadIdx.x;
  for (int t = tid; t < NBLK; t += 64) removedL[t] = 0ull;
  __syncthreads();
  int total = 0;
  u32 c_cur = counts[tid]; c_cur = (c_cur < (u32)CAP) ? c_cur : (u32)CAP;
  u64 iv_cur = intra[tid];
  float4 b_cur = bS[tid];
  for (int rb = 0; rb < NBLK; ++rb) {
    u32 c_nxt = 0; u64 iv_nxt = 0; float4 b_nxt = make_float4(0, 0, 0, 0);
    if (rb + 1 < NBLK) {
      int ni = (rb + 1) * 64 + tid;
      c_nxt = counts[ni]; c_nxt = (c_nxt < (u32)CAP) ? c_nxt : (u32)CAP;
      iv_nxt = intra[ni];
      b_nxt = bS[ni];
    }
    u64 r = removedL[rb];
    u64 cand = ~r;
    u64 iw = __ballot(iv_cur != 0ull);
    if (cand & iw) {
      u64 rr = r;
      for (int k = 0; k < 64; ++k) {
        u64 mk = __shfl(iv_cur, k, 64);
        if (!((rr >> k) & 1ull)) rr |= mk;
      }
      cand = ~rr;
    }
    u64 kw = cand;
    bool keep = (kw >> tid) & 1ull;
    int rank = total + __popcll(kw & ((1ull << tid) - 1ull));
    if (keep && rank < PROP) out[rank] = b_cur;
    total += __popcll(kw);
    if (total >= PROP) break;
    if (keep && c_cur > 0) {
      const u16* e = entries + (u32)(rb * 64 + tid) * CAP;
      for (u32 q = 0; q < c_cur; ++q) {
        int j = e[q];
        atomicOr(&removedL[j >> 6], 1ull << (j & 63));
      }
    }
    __syncthreads();
    c_cur = c_nxt; iv_cur = iv_nxt; b_cur = b_nxt;
  }
  int tk = (total < PROP) ? total : PROP;
  for (int s = tk + tid; s < PROP; s += 64)
    out[s] = make_float4(0.f, 0.f, 0.f, 0.f);
}

// --------------------------------------------------------------------------
extern "C" void kernel_launch(void* const* d_in, const int* in_sizes, int n_in,
                              void* d_out, int out_size, void* d_ws, size_t ws_size,
                              hipStream_t stream)
{
  const float* cls  = (const float*)d_in[0];   // rpn_class  (16384,1)
  const float* bbox = (const float*)d_in[1];   // rpn_bbox   (16384,4)
  const float* anch = (const float*)d_in[2];   // anchors    (16384,4)

  uint8_t* w = (uint8_t*)d_ws;
  float4* boxes_u = (float4*)(w);                    // 256 KB
  u64*    keys    = (u64*)(w + (256 << 10));         // 128 KB
  float4* bS      = (float4*)(w + (384 << 10));      // 256 KB
  float*  areaS   = (float*)(w + (640 << 10));       //  64 KB
  u32*    counts  = (u32*)(w + (704 << 10));         //  64 KB
  u64*    intra   = (u64*)(w + (768 << 10));         // 128 KB
  u32*    rankArr = (u32*)(w + (896 << 10));         //  64 KB
  u16*    entries = (u16*)(w + (960 << 10));         //   2 MB
  float4* out     = (float4*)d_out;                  // 2000 x float4

  decode_kernel<<<64, 256, 0, stream>>>(cls, bbox, anch, boxes_u, keys);
  init_kernel<<<64, 256, 0, stream>>>(counts, rankArr);
  rank_kernel<<<dim3(256, RANK_CY), 256, 0, stream>>>(keys, rankArr);
  scatter_kernel<<<64, 256, 0, stream>>>(rankArr, boxes_u, bS, areaS);
  mask_kernel<<<NPAIRS, 256, 0, stream>>>(bS, areaS, counts, intra, entries);
  resolve_kernel<<<1, 64, 0, stream>>>(counts, intra, entries, bS, out);
}

// Round 4
// 79.750 us; speedup vs baseline: 17.9133x; 2.3087x over previous
//
#include <hip/hip_runtime.h>
#include <cstdint>

#define N_ANCH 16384
#define NBLK 256      // 64-box blocks in full problem
#define CAP 64        // max cross-block suppression targets stored per row
#define PROP 2000

// ---- phase-1 (prefix) NMS: only first M1 sorted rows/cols ----
#define M1 4096
#define T1 128
#define NT1 (M1 / T1)                 // 32
#define NP1 (NT1 * (NT1 + 1) / 2)     // 528 tile-pair blocks
#define NBLK1 (M1 / 64)               // 64 resolve blocks

// ---- full fallback mask ----
#define TILE 256
#define NT (N_ANCH / TILE)            // 64
#define NPAIRS (NT * (NT + 1) / 2)    // 2080

typedef unsigned long long u64;
typedef unsigned int u32;
typedef unsigned short u16;

#define C_HI (0.7f * 1.00002f)
#define C_LO (0.7f * 0.99998f)

// ---------------- Kernel A: decode + zero-init everything -----------------
__global__ __launch_bounds__(256) void decode_init_kernel(
    const float* __restrict__ cls, const float* __restrict__ bbox,
    const float* __restrict__ anch, float4* __restrict__ boxes_u,
    u64* __restrict__ keys, u32* __restrict__ counts,
    u64* __restrict__ intra, u32* __restrict__ rankArr, u32* __restrict__ flag)
{
  int i = blockIdx.x * 256 + threadIdx.x;
  counts[i] = 0u;
  intra[i] = 0ull;
  rankArr[i] = 0u;
  if (i == 0) *flag = 0u;
  float s = cls[i];
  float4 bb = ((const float4*)bbox)[i];
  float4 aa = ((const float4*)anch)[i];
  float d0 = s * bb.x, d1 = s * bb.y, d2 = s * bb.z, d3 = s * bb.w;
  float wa = aa.z - aa.x;
  float ha = aa.w - aa.y;
  float cx = aa.x + 0.5f * wa + d0 * wa;
  float cy = aa.y + 0.5f * ha + d1 * ha;
  float w = wa * expf(d2);
  float h = ha * expf(d3);
  float x1 = fmaxf(cx - 0.5f * w, 0.f);
  float y1 = fmaxf(cy - 0.5f * h, 0.f);
  float x2 = fminf(cx + 0.5f * w, 1023.f);
  float y2 = fminf(cy + 0.5f * h, 1023.f);
  boxes_u[i] = make_float4(x1, y1, x2, y2);
  u32 sb = __float_as_uint(s);
  keys[i] = ((u64)(sb ^ 0xFFFFFFFFu) << 32) | (u32)i;
}

// ---------------- Kernel B: rank via register-blocked enumeration ---------
// grid (16, 32): block (rb, cb). 4 row-keys per thread in VGPRs; 512-key
// column chunk staged in LDS, read broadcast-uniform (1 ds_read / 8 cmps).
__global__ __launch_bounds__(256) void rank_kernel(
    const u64* __restrict__ keys, u32* __restrict__ rankArr)
{
  __shared__ u64 kt[512];
  int tid = threadIdx.x;
  int r0 = blockIdx.x * 1024 + tid;
  int cb = blockIdx.y * 512;
  u64 k0 = keys[r0];
  u64 k1 = keys[r0 + 256];
  u64 k2 = keys[r0 + 512];
  u64 k3 = keys[r0 + 768];
  kt[tid] = keys[cb + tid];
  kt[tid + 256] = keys[cb + tid + 256];
  __syncthreads();
  int c0 = 0, c1 = 0, c2 = 0, c3 = 0;
#pragma unroll 16
  for (int q = 0; q < 512; ++q) {
    u64 k = kt[q];
    c0 += (k < k0);
    c1 += (k < k1);
    c2 += (k < k2);
    c3 += (k < k3);
  }
  atomicAdd(&rankArr[r0], (u32)c0);
  atomicAdd(&rankArr[r0 + 256], (u32)c1);
  atomicAdd(&rankArr[r0 + 512], (u32)c2);
  atomicAdd(&rankArr[r0 + 768], (u32)c3);
}

// ---------------- Kernel B2: scatter boxes into sorted order --------------
__global__ __launch_bounds__(256) void scatter_kernel(
    const u32* __restrict__ rankArr, const float4* __restrict__ boxes_u,
    float4* __restrict__ bS, float* __restrict__ areaS)
{
  int i = blockIdx.x * 256 + threadIdx.x;
  u32 r = rankArr[i];
  float4 b = boxes_u[i];
  bS[r] = b;
  areaS[r] = (b.z - b.x) * (b.w - b.y);
}

// ---------------- shared IoU chunk helper (64 j's, branchless) ------------
__device__ __forceinline__ u64 iou_chunk(
    const float4 bi, const float ai, const float4* bp, const float* ap)
{
  u32 mlo = 0u, mhi = 0u;
#pragma unroll
  for (int qq = 0; qq < 64; ++qq) {
    float4 bj = bp[qq];
    float aj = ap[qq];
    float dx = fminf(bi.z, bj.z) - fmaxf(bi.x, bj.x);
    float dy = fminf(bi.w, bj.w) - fmaxf(bi.y, bj.y);
    float inter = fmaxf(dx, 0.f) * fmaxf(dy, 0.f);
    float um = fmaxf(ai + aj - inter, 1e-8f);
    bool hi = inter > um * C_HI;
    bool lo = inter > um * C_LO;
    if (hi != lo) hi = (inter / um) > 0.7f;  // rare exact IEEE fallback
    if (qq < 32) mlo |= hi ? (1u << qq) : 0u;
    else         mhi |= hi ? (1u << (qq - 32)) : 0u;
  }
  return ((u64)mhi << 32) | (u64)mlo;
}

// ---------------- Kernel C1: prefix mask (first M1 rows/cols) -------------
// 528 blocks over (ta<=tb) 128x128 tile pairs; thread = (row-in-tile, col-half)
__global__ __launch_bounds__(256) void mask1_kernel(
    const float4* __restrict__ bS, const float* __restrict__ areaS,
    u32* __restrict__ counts, u64* __restrict__ intra,
    u16* __restrict__ entries)
{
  __shared__ float4 bT[T1];
  __shared__ float aT[T1];
  int tid = threadIdx.x;
  int rem = blockIdx.x;
  int ta = 0, rowlen = NT1;
  while (rem >= rowlen) { rem -= rowlen; ++ta; --rowlen; }
  int tb = ta + rem;

  int il = tid & 127;
  int h = tid >> 7;           // which 64-col chunk of the j-tile
  int i = ta * T1 + il;
  int jbase = tb * T1;
  if (tid < T1) {
    float4 b = bS[jbase + tid];
    bT[tid] = b;
    aT[tid] = areaS[jbase + tid];
  }
  float4 bi = bS[i];
  float ai = areaS[i];
  __syncthreads();

  const float4* bp = &bT[h * 64];
  const float* ap = &aT[h * 64];
  int jb = jbase + h * 64;

  u64 m;
  if (ta == tb) {
    int bi_blk = il >> 6;
    if (h < bi_blk) return;              // chunk entirely j <= i
    m = iou_chunk(bi, ai, bp, ap);
    if (h == bi_blk) {                   // same 64-block: triangular intra
      int lane = il & 63;
      m &= (~1ull) << lane;              // keep j > i only
      intra[i] = m;
      return;
    }
  } else {
    m = iou_chunk(bi, ai, bp, ap);
  }
  // cross-64-block sparse flush
  while (m) {
    int b = __builtin_ctzll(m);
    m &= m - 1;
    u32 p = atomicAdd(&counts[i], 1u);
    if (p < CAP) entries[(u32)i * CAP + p] = (u16)(jb + b);
  }
}

// ---------------- Kernel D1: prefix resolve; sets done flag ---------------
__global__ __launch_bounds__(64) void resolve1_kernel(
    const u32* __restrict__ counts, const u64* __restrict__ intra,
    const u16* __restrict__ entries, const float4* __restrict__ bS,
    float4* __restrict__ out, u32* __restrict__ flag)
{
  __shared__ u64 removedL[NBLK1];
  int tid = threadIdx.x;
  removedL[tid] = 0ull;
  __syncthreads();
  int total = 0;
  u32 c_cur = counts[tid]; c_cur = (c_cur < (u32)CAP) ? c_cur : (u32)CAP;
  u64 iv_cur = intra[tid];
  float4 b_cur = bS[tid];
  for (int rb = 0; rb < NBLK1; ++rb) {
    u32 c_nxt = 0; u64 iv_nxt = 0; float4 b_nxt = make_float4(0, 0, 0, 0);
    if (rb + 1 < NBLK1) {
      int ni = (rb + 1) * 64 + tid;
      c_nxt = counts[ni]; c_nxt = (c_nxt < (u32)CAP) ? c_nxt : (u32)CAP;
      iv_nxt = intra[ni];
      b_nxt = bS[ni];
    }
    u64 r = removedL[rb];
    u64 cand = ~r;
    u64 iw = __ballot(iv_cur != 0ull);
    if (cand & iw) {
      u64 rr = r;
      for (int k = 0; k < 64; ++k) {
        u64 mk = __shfl(iv_cur, k, 64);
        if (!((rr >> k) & 1ull)) rr |= mk;
      }
      cand = ~rr;
    }
    u64 kw = cand;
    bool keep = (kw >> tid) & 1ull;
    int rank = total + __popcll(kw & ((1ull << tid) - 1ull));
    if (keep && rank < PROP) out[rank] = b_cur;
    total += __popcll(kw);
    if (total >= PROP) break;
    if (keep && c_cur > 0) {
      const u16* e = entries + (u32)(rb * 64 + tid) * CAP;
      for (u32 q = 0; q < c_cur; ++q) {
        int j = e[q];
        atomicOr(&removedL[j >> 6], 1ull << (j & 63));
      }
    }
    __syncthreads();
    c_cur = c_nxt; iv_cur = iv_nxt; b_cur = b_nxt;
  }
  int tk = (total < PROP) ? total : PROP;
  for (int s = tk + tid; s < PROP; s += 64)
    out[s] = make_float4(0.f, 0.f, 0.f, 0.f);
  if (tid == 0) *flag = (total >= PROP) ? 1u : 0u;
}

// ---------------- Fallback chain (no-ops when flag==1) --------------------
__global__ __launch_bounds__(256) void init2_kernel(
    u32* __restrict__ counts, u64* __restrict__ intra,
    const u32* __restrict__ flag)
{
  if (*flag) return;
  int i = blockIdx.x * 256 + threadIdx.x;
  counts[i] = 0u;
  intra[i] = 0ull;
}

__global__ __launch_bounds__(256) void mask_full_kernel(
    const float4* __restrict__ bS, const float* __restrict__ areaS,
    u32* __restrict__ counts, u64* __restrict__ intra,
    u16* __restrict__ entries, const u32* __restrict__ flag)
{
  if (*flag) return;
  __shared__ float4 bT[TILE];
  __shared__ float aT[TILE];
  int tid = threadIdx.x;
  int rem = blockIdx.x;
  int ta = 0, rowlen = NT;
  while (rem >= rowlen) { rem -= rowlen; ++ta; --rowlen; }
  int tb = ta + rem;

  int i = ta * TILE + tid;
  float4 bi = bS[i];
  float ai = areaS[i];
  int jbase = tb * TILE;
  bT[tid] = bS[jbase + tid];
  aT[tid] = areaS[jbase + tid];
  __syncthreads();

  auto flush = [&](u64 m, int ch) {
    int jb = jbase + ch * 64;
    while (m) {
      int b = __builtin_ctzll(m);
      m &= m - 1;
      u32 p = atomicAdd(&counts[i], 1u);
      if (p < CAP) entries[(u32)i * CAP + p] = (u16)(jb + b);
    }
  };

  if (ta == tb) {
    int wave = tid >> 6, lane = tid & 63;
    u64 m = iou_chunk(bi, ai, &bT[wave * 64], &aT[wave * 64]);
    m &= (~1ull) << lane;
    intra[i] = m;
    for (int ch = wave + 1; ch < 4; ++ch)
      flush(iou_chunk(bi, ai, &bT[ch * 64], &aT[ch * 64]), ch);
  } else {
#pragma unroll
    for (int ch = 0; ch < 4; ++ch)
      flush(iou_chunk(bi, ai, &bT[ch * 64], &aT[ch * 64]), ch);
  }
}

__global__ __launch_bounds__(64) void resolve_full_kernel(
    const u32* __restrict__ counts, const u64* __restrict__ intra,
    const u16* __restrict__ entries, const float4* __restrict__ bS,
    float4* __restrict__ out, const u32* __restrict__ flag)
{
  if (*flag) return;
  __shared__ u64 removedL[NBLK];
  int tid = threadIdx.x;
  for (int t = tid; t < NBLK; t += 64) removedL[t] = 0ull;
  __syncthreads();
  int total = 0;
  u32 c_cur = counts[tid]; c_cur = (c_cur < (u32)CAP) ? c_cur : (u32)CAP;
  u64 iv_cur = intra[tid];
  float4 b_cur = bS[tid];
  for (int rb = 0; rb < NBLK; ++rb) {
    u32 c_nxt = 0; u64 iv_nxt = 0; float4 b_nxt = make_float4(0, 0, 0, 0);
    if (rb + 1 < NBLK) {
      int ni = (rb + 1) * 64 + tid;
      c_nxt = counts[ni]; c_nxt = (c_nxt < (u32)CAP) ? c_nxt : (u32)CAP;
      iv_nxt = intra[ni];
      b_nxt = bS[ni];
    }
    u64 r = removedL[rb];
    u64 cand = ~r;
    u64 iw = __ballot(iv_cur != 0ull);
    if (cand & iw) {
      u64 rr = r;
      for (int k = 0; k < 64; ++k) {
        u64 mk = __shfl(iv_cur, k, 64);
        if (!((rr >> k) & 1ull)) rr |= mk;
      }
      cand = ~rr;
    }
    u64 kw = cand;
    bool keep = (kw >> tid) & 1ull;
    int rank = total + __popcll(kw & ((1ull << tid) - 1ull));
    if (keep && rank < PROP) out[rank] = b_cur;
    total += __popcll(kw);
    if (total >= PROP) break;
    if (keep && c_cur > 0) {
      const u16* e = entries + (u32)(rb * 64 + tid) * CAP;
      for (u32 q = 0; q < c_cur; ++q) {
        int j = e[q];
        atomicOr(&removedL[j >> 6], 1ull << (j & 63));
      }
    }
    __syncthreads();
    c_cur = c_nxt; iv_cur = iv_nxt; b_cur = b_nxt;
  }
  int tk = (total < PROP) ? total : PROP;
  for (int s = tk + tid; s < PROP; s += 64)
    out[s] = make_float4(0.f, 0.f, 0.f, 0.f);
}

// --------------------------------------------------------------------------
extern "C" void kernel_launch(void* const* d_in, const int* in_sizes, int n_in,
                              void* d_out, int out_size, void* d_ws, size_t ws_size,
                              hipStream_t stream)
{
  const float* cls  = (const float*)d_in[0];   // rpn_class  (16384,1)
  const float* bbox = (const float*)d_in[1];   // rpn_bbox   (16384,4)
  const float* anch = (const float*)d_in[2];   // anchors    (16384,4)

  uint8_t* w = (uint8_t*)d_ws;
  float4* boxes_u = (float4*)(w);                    // 256 KB
  u64*    keys    = (u64*)(w + (256 << 10));         // 128 KB
  float4* bS      = (float4*)(w + (384 << 10));      // 256 KB
  float*  areaS   = (float*)(w + (640 << 10));       //  64 KB
  u32*    counts  = (u32*)(w + (704 << 10));         //  64 KB
  u64*    intra   = (u64*)(w + (768 << 10));         // 128 KB
  u32*    rankArr = (u32*)(w + (896 << 10));         //  64 KB
  u32*    flag    = (u32*)(w + (960 << 10));         //   4 B
  u16*    entries = (u16*)(w + (1 << 20));           //   2 MB
  float4* out     = (float4*)d_out;                  // 2000 x float4

  decode_init_kernel<<<64, 256, 0, stream>>>(cls, bbox, anch, boxes_u, keys,
                                             counts, intra, rankArr, flag);
  rank_kernel<<<dim3(16, 32), 256, 0, stream>>>(keys, rankArr);
  scatter_kernel<<<64, 256, 0, stream>>>(rankArr, boxes_u, bS, areaS);
  mask1_kernel<<<NP1, 256, 0, stream>>>(bS, areaS, counts, intra, entries);
  resolve1_kernel<<<1, 64, 0, stream>>>(counts, intra, entries, bS, out, flag);
  init2_kernel<<<64, 256, 0, stream>>>(counts, intra, flag);
  mask_full_kernel<<<NPAIRS, 256, 0, stream>>>(bS, areaS, counts, intra,
                                               entries, flag);
  resolve_full_kernel<<<1, 64, 0, stream>>>(counts, intra, entries, bS, out,
                                            flag);
}

// Round 5
// 77.622 us; speedup vs baseline: 18.4045x; 1.0274x over previous
//
#include <hip/hip_runtime.h>
#include <cstdint>

typedef unsigned long long u64;
typedef unsigned int u32;
typedef unsigned short u16;

#define N_ANCH 16384
#define PROP 2000
#define CAP 64
#define TAU 0.75f

// ---- fast path: selected prefix (score > TAU), capacity KMAX ----
#define KMAX 4608
#define NBLK1 (KMAX / 64)              // 72
#define T1 128
#define NT1 (KMAX / T1)                // 36
#define NP1 (NT1 * (NT1 + 1) / 2)      // 666
#define SEL_RB (KMAX / 256)            // 18 row blocks for rank_sel
#define SEL_CB ((KMAX + 511) / 512)    // 9 col chunks

// ---- gated full fallback ----
#define TILE 256
#define NT (N_ANCH / TILE)             // 64
#define NPAIRS (NT * (NT + 1) / 2)     // 2080
#define NBLKF (N_ANCH / 64)            // 256

#define C_HI (0.7f * 1.00002f)
#define C_LO (0.7f * 0.99998f)

__device__ __forceinline__ u64 shfl64(u64 v, int src) {
  int lo = __shfl((int)(u32)(v & 0xffffffffull), src, 64);
  int hi = __shfl((int)(u32)(v >> 32), src, 64);
  return ((u64)(u32)hi << 32) | (u64)(u32)lo;
}

// ---------------- shared IoU chunk helper (64 j's, branchless) ------------
__device__ __forceinline__ u64 iou_chunk(
    const float4 bi, const float ai, const float4* bp, const float* ap)
{
  u32 mlo = 0u, mhi = 0u;
#pragma unroll
  for (int qq = 0; qq < 64; ++qq) {
    float4 bj = bp[qq];
    float aj = ap[qq];
    float dx = fminf(bi.z, bj.z) - fmaxf(bi.x, bj.x);
    float dy = fminf(bi.w, bj.w) - fmaxf(bi.y, bj.y);
    float inter = fmaxf(dx, 0.f) * fmaxf(dy, 0.f);
    float um = fmaxf(ai + aj - inter, 1e-8f);
    bool hi = inter > um * C_HI;
    bool lo = inter > um * C_LO;
    if (hi != lo) hi = (inter / um) > 0.7f;  // rare exact IEEE fallback
    if (qq < 32) mlo |= hi ? (1u << qq) : 0u;
    else         mhi |= hi ? (1u << (qq - 32)) : 0u;
  }
  return ((u64)mhi << 32) | (u64)mlo;
}

// ---------------- Kernel 1: decode + select + zero-init -------------------
__global__ __launch_bounds__(256) void decode_select_kernel(
    const float* __restrict__ cls, const float* __restrict__ bbox,
    const float* __restrict__ anch, float4* __restrict__ boxes_u,
    u64* __restrict__ keysF,
    u32* __restrict__ countsF, u64* __restrict__ intraF,
    u32* __restrict__ rankArrF, u32* __restrict__ arriveF,
    u32* __restrict__ counts1, u64* __restrict__ intra1,
    u32* __restrict__ rankSel, u32* __restrict__ arriveSel,
    float4* __restrict__ bSel, float* __restrict__ areaSel,
    u64* __restrict__ selKeys, u32* __restrict__ selIdx,
    u32* __restrict__ selCount)
{
  int i = blockIdx.x * 256 + threadIdx.x;
  countsF[i] = 0u; intraF[i] = 0ull; rankArrF[i] = 0u; arriveF[i] = 0u;
  if (i < KMAX) {
    counts1[i] = 0u; intra1[i] = 0ull; rankSel[i] = 0u; arriveSel[i] = 0u;
    bSel[i] = make_float4(0.f, 0.f, 0.f, 0.f); areaSel[i] = 0.f;
  }
  float s = cls[i];
  float4 bb = ((const float4*)bbox)[i];
  float4 aa = ((const float4*)anch)[i];
  float d0 = s * bb.x, d1 = s * bb.y, d2 = s * bb.z, d3 = s * bb.w;
  float wa = aa.z - aa.x;
  float ha = aa.w - aa.y;
  float cx = aa.x + 0.5f * wa + d0 * wa;
  float cy = aa.y + 0.5f * ha + d1 * ha;
  float w = wa * expf(d2);
  float h = ha * expf(d3);
  float x1 = fmaxf(cx - 0.5f * w, 0.f);
  float y1 = fmaxf(cy - 0.5f * h, 0.f);
  float x2 = fminf(cx + 0.5f * w, 1023.f);
  float y2 = fminf(cy + 0.5f * h, 1023.f);
  boxes_u[i] = make_float4(x1, y1, x2, y2);
  u32 sb = __float_as_uint(s);
  u64 key = ((u64)(sb ^ 0xFFFFFFFFu) << 32) | (u32)i;
  keysF[i] = key;
  if (s > TAU) {
    u32 p = atomicAdd(selCount, 1u);
    if (p < KMAX) { selKeys[p] = key; selIdx[p] = i; }
  }
}

// ---------------- Kernel 2: rank within selected set + fused scatter ------
// grid (18, 9): block (rb, cb). One row/thread; 512-key col chunk in LDS.
__global__ __launch_bounds__(256) void rank_sel_kernel(
    const u64* __restrict__ selKeys, const u32* __restrict__ selIdx,
    const float4* __restrict__ boxes_u, u32* __restrict__ rankSel,
    u32* __restrict__ arriveSel, float4* __restrict__ bSel,
    float* __restrict__ areaSel, const u32* __restrict__ selCount)
{
  __shared__ u64 kt[512];
  int tid = threadIdx.x;
  u32 Kraw = *selCount;
  u32 Kc = Kraw < (u32)KMAX ? Kraw : (u32)KMAX;
  int r = blockIdx.x * 256 + tid;
  int cb = blockIdx.y * 512;
  int i0 = cb + tid, i1 = cb + 256 + tid;
  kt[tid] = (i0 < (int)Kc) ? selKeys[i0] : ~0ull;
  kt[tid + 256] = (i1 < (int)Kc) ? selKeys[i1] : ~0ull;
  bool active = r < (int)Kc;
  u64 ki = active ? selKeys[r] : 0ull;
  __syncthreads();
  if (!active) return;
  int cnt = 0;
#pragma unroll 16
  for (int q = 0; q < 512; ++q)
    cnt += (kt[q] < ki);
  atomicAdd(&rankSel[r], (u32)cnt);
  __threadfence();
  u32 old = atomicAdd(&arriveSel[r], 1u);
  if (old == SEL_CB - 1) {              // last arriver: rank final
    u32 rr = atomicAdd(&rankSel[r], 0u);  // coherent read
    int oi = selIdx[r];
    float4 b = boxes_u[oi];
    bSel[rr] = b;
    areaSel[rr] = (b.z - b.x) * (b.w - b.y);
  }
}

// ---------------- Kernel 3: prefix mask over selected, KMAX rows ----------
__global__ __launch_bounds__(256) void mask1_kernel(
    const float4* __restrict__ bSel, const float* __restrict__ areaSel,
    u32* __restrict__ counts1, u64* __restrict__ intra1,
    u16* __restrict__ entries1)
{
  __shared__ float4 bT[T1];
  __shared__ float aT[T1];
  int tid = threadIdx.x;
  int rem = blockIdx.x;
  int ta = 0, rowlen = NT1;
  while (rem >= rowlen) { rem -= rowlen; ++ta; --rowlen; }
  int tb = ta + rem;

  int il = tid & 127;
  int h = tid >> 7;
  int i = ta * T1 + il;
  int jbase = tb * T1;
  if (tid < T1) {
    bT[tid] = bSel[jbase + tid];
    aT[tid] = areaSel[jbase + tid];
  }
  float4 bi = bSel[i];
  float ai = areaSel[i];
  __syncthreads();

  const float4* bp = &bT[h * 64];
  const float* ap = &aT[h * 64];
  int jb = jbase + h * 64;

  u64 m;
  if (ta == tb) {
    int bi_blk = il >> 6;
    if (h < bi_blk) return;
    m = iou_chunk(bi, ai, bp, ap);
    if (h == bi_blk) {
      int lane = il & 63;
      m &= (~1ull) << lane;
      intra1[i] = m;
      return;
    }
  } else {
    m = iou_chunk(bi, ai, bp, ap);
  }
  while (m) {
    int b = __builtin_ctzll(m);
    m &= m - 1;
    u32 p = atomicAdd(&counts1[i], 1u);
    if (p < CAP) entries1[(u32)i * CAP + p] = (u16)(jb + b);
  }
}

// ---------------- Kernel 4: prefix greedy resolve; sets flag --------------
__global__ __launch_bounds__(64) void resolve1_kernel(
    const u32* __restrict__ counts1, const u64* __restrict__ intra1,
    const u16* __restrict__ entries1, const float4* __restrict__ bSel,
    const u32* __restrict__ selCount, float4* __restrict__ out,
    u32* __restrict__ flag)
{
  __shared__ u64 removedL[NBLK1];
  int tid = threadIdx.x;
  for (int t = tid; t < NBLK1; t += 64) removedL[t] = 0ull;
  __syncthreads();
  u32 Kraw = *selCount;
  u32 Kc = Kraw < (u32)KMAX ? Kraw : (u32)KMAX;
  int nb = (int)((Kc + 63) >> 6);
  int total = 0;
  u32 c_cur = counts1[tid]; c_cur = (c_cur < (u32)CAP) ? c_cur : (u32)CAP;
  u64 iv_cur = intra1[tid];
  float4 b_cur = bSel[tid];
  for (int rb = 0; rb < nb; ++rb) {
    u32 c_nxt = 0; u64 iv_nxt = 0; float4 b_nxt = make_float4(0, 0, 0, 0);
    if (rb + 1 < nb) {
      int ni = (rb + 1) * 64 + tid;
      c_nxt = counts1[ni]; c_nxt = (c_nxt < (u32)CAP) ? c_nxt : (u32)CAP;
      iv_nxt = intra1[ni];
      b_nxt = bSel[ni];
    }
    u64 rr = removedL[rb];
    // sparse intra-block greedy chain: only alive lanes with intra bits
    u64 work = __ballot(iv_cur != 0ull) & ~rr;
    while (work) {
      int k = __builtin_ctzll(work);
      work &= work - 1;
      rr |= shfl64(iv_cur, k);
      work &= ~rr;
    }
    u64 kw = ~rr;
    if (rb == nb - 1 && (Kc & 63u)) kw &= (1ull << (Kc & 63u)) - 1ull;
    bool keep = (kw >> tid) & 1ull;
    int rank = total + __popcll(kw & ((1ull << tid) - 1ull));
    if (keep && rank < PROP) out[rank] = b_cur;
    total += __popcll(kw);
    if (total >= PROP) break;
    if (keep && c_cur > 0) {
      const u16* e = entries1 + (u32)(rb * 64 + tid) * CAP;
      for (u32 q = 0; q < c_cur; ++q) {
        int j = e[q];
        atomicOr(&removedL[j >> 6], 1ull << (j & 63));
      }
    }
    __syncthreads();
    c_cur = c_nxt; iv_cur = iv_nxt; b_cur = b_nxt;
  }
  int tk = (total < PROP) ? total : PROP;
  for (int s = tk + tid; s < PROP; s += 64)
    out[s] = make_float4(0.f, 0.f, 0.f, 0.f);
  if (tid == 0) *flag = (total >= PROP && Kraw <= (u32)KMAX) ? 1u : 0u;
}

// ================= gated fallback chain (flag==0 only) ====================
// ---------------- full rank + fused scatter --------------------------------
__global__ __launch_bounds__(256) void rank_full_kernel(
    const u64* __restrict__ keysF, const float4* __restrict__ boxes_u,
    u32* __restrict__ rankArrF, u32* __restrict__ arriveF,
    float4* __restrict__ bSF, float* __restrict__ areaSF,
    const u32* __restrict__ flag)
{
  if (*flag) return;
  __shared__ u64 kt[512];
  int tid = threadIdx.x;
  int r0 = blockIdx.x * 1024 + tid;
  int cb = blockIdx.y * 512;
  u64 k0 = keysF[r0];
  u64 k1 = keysF[r0 + 256];
  u64 k2 = keysF[r0 + 512];
  u64 k3 = keysF[r0 + 768];
  kt[tid] = keysF[cb + tid];
  kt[tid + 256] = keysF[cb + tid + 256];
  __syncthreads();
  int c0 = 0, c1 = 0, c2 = 0, c3 = 0;
#pragma unroll 16
  for (int q = 0; q < 512; ++q) {
    u64 k = kt[q];
    c0 += (k < k0);
    c1 += (k < k1);
    c2 += (k < k2);
    c3 += (k < k3);
  }
  atomicAdd(&rankArrF[r0], (u32)c0);
  atomicAdd(&rankArrF[r0 + 256], (u32)c1);
  atomicAdd(&rankArrF[r0 + 512], (u32)c2);
  atomicAdd(&rankArrF[r0 + 768], (u32)c3);
  __threadfence();
#pragma unroll
  for (int m = 0; m < 4; ++m) {
    int row = r0 + m * 256;
    u32 old = atomicAdd(&arriveF[row], 1u);
    if (old == 31u) {
      u32 rr = atomicAdd(&rankArrF[row], 0u);
      float4 b = boxes_u[row];
      bSF[rr] = b;
      areaSF[rr] = (b.z - b.x) * (b.w - b.y);
    }
  }
}

// ---------------- full mask -------------------------------------------------
__global__ __launch_bounds__(256) void mask_full_kernel(
    const float4* __restrict__ bSF, const float* __restrict__ areaSF,
    u32* __restrict__ countsF, u64* __restrict__ intraF,
    u16* __restrict__ entriesF, const u32* __restrict__ flag)
{
  if (*flag) return;
  __shared__ float4 bT[TILE];
  __shared__ float aT[TILE];
  int tid = threadIdx.x;
  int rem = blockIdx.x;
  int ta = 0, rowlen = NT;
  while (rem >= rowlen) { rem -= rowlen; ++ta; --rowlen; }
  int tb = ta + rem;

  int i = ta * TILE + tid;
  float4 bi = bSF[i];
  float ai = areaSF[i];
  int jbase = tb * TILE;
  bT[tid] = bSF[jbase + tid];
  aT[tid] = areaSF[jbase + tid];
  __syncthreads();

  auto flush = [&](u64 m, int ch) {
    int jb = jbase + ch * 64;
    while (m) {
      int b = __builtin_ctzll(m);
      m &= m - 1;
      u32 p = atomicAdd(&countsF[i], 1u);
      if (p < CAP) entriesF[(u32)i * CAP + p] = (u16)(jb + b);
    }
  };

  if (ta == tb) {
    int wave = tid >> 6, lane = tid & 63;
    u64 m = iou_chunk(bi, ai, &bT[wave * 64], &aT[wave * 64]);
    m &= (~1ull) << lane;
    intraF[i] = m;
    for (int ch = wave + 1; ch < 4; ++ch)
      flush(iou_chunk(bi, ai, &bT[ch * 64], &aT[ch * 64]), ch);
  } else {
#pragma unroll
    for (int ch = 0; ch < 4; ++ch)
      flush(iou_chunk(bi, ai, &bT[ch * 64], &aT[ch * 64]), ch);
  }
}

// ---------------- full resolve ---------------------------------------------
__global__ __launch_bounds__(64) void resolve_full_kernel(
    const u32* __restrict__ countsF, const u64* __restrict__ intraF,
    const u16* __restrict__ entriesF, const float4* __restrict__ bSF,
    float4* __restrict__ out, const u32* __restrict__ flag)
{
  if (*flag) return;
  __shared__ u64 removedL[NBLKF];
  int tid = threadIdx.x;
  for (int t = tid; t < NBLKF; t += 64) removedL[t] = 0ull;
  __syncthreads();
  int total = 0;
  u32 c_cur = countsF[tid]; c_cur = (c_cur < (u32)CAP) ? c_cur : (u32)CAP;
  u64 iv_cur = intraF[tid];
  float4 b_cur = bSF[tid];
  for (int rb = 0; rb < NBLKF; ++rb) {
    u32 c_nxt = 0; u64 iv_nxt = 0; float4 b_nxt = make_float4(0, 0, 0, 0);
    if (rb + 1 < NBLKF) {
      int ni = (rb + 1) * 64 + tid;
      c_nxt = countsF[ni]; c_nxt = (c_nxt < (u32)CAP) ? c_nxt : (u32)CAP;
      iv_nxt = intraF[ni];
      b_nxt = bSF[ni];
    }
    u64 rr = removedL[rb];
    u64 work = __ballot(iv_cur != 0ull) & ~rr;
    while (work) {
      int k = __builtin_ctzll(work);
      work &= work - 1;
      rr |= shfl64(iv_cur, k);
      work &= ~rr;
    }
    u64 kw = ~rr;
    bool keep = (kw >> tid) & 1ull;
    int rank = total + __popcll(kw & ((1ull << tid) - 1ull));
    if (keep && rank < PROP) out[rank] = b_cur;
    total += __popcll(kw);
    if (total >= PROP) break;
    if (keep && c_cur > 0) {
      const u16* e = entriesF + (u32)(rb * 64 + tid) * CAP;
      for (u32 q = 0; q < c_cur; ++q) {
        int j = e[q];
        atomicOr(&removedL[j >> 6], 1ull << (j & 63));
      }
    }
    __syncthreads();
    c_cur = c_nxt; iv_cur = iv_nxt; b_cur = b_nxt;
  }
  int tk = (total < PROP) ? total : PROP;
  for (int s = tk + tid; s < PROP; s += 64)
    out[s] = make_float4(0.f, 0.f, 0.f, 0.f);
}

// --------------------------------------------------------------------------
extern "C" void kernel_launch(void* const* d_in, const int* in_sizes, int n_in,
                              void* d_out, int out_size, void* d_ws, size_t ws_size,
                              hipStream_t stream)
{
  const float* cls  = (const float*)d_in[0];
  const float* bbox = (const float*)d_in[1];
  const float* anch = (const float*)d_in[2];

  uint8_t* w = (uint8_t*)d_ws;
  float4* boxes_u = (float4*)(w);                      // 256 KB
  u64*    keysF   = (u64*)(w + (256 << 10));           // 128 KB
  float4* bSF     = (float4*)(w + (384 << 10));        // 256 KB
  float*  areaSF  = (float*)(w + (640 << 10));         //  64 KB
  u32*    countsF = (u32*)(w + (704 << 10));           //  64 KB
  u64*    intraF  = (u64*)(w + (768 << 10));           // 128 KB
  u32*    rankArrF= (u32*)(w + (896 << 10));           //  64 KB
  u32*    arriveF = (u32*)(w + (960 << 10));           //  64 KB
  u16*    entriesF= (u16*)(w + (1 << 20));             //   2 MB
  u64*    selKeys = (u64*)(w + (3 << 20));             //  64 KB
  u32*    selIdx  = (u32*)(w + (3 << 20) + (64 << 10));// 64 KB
  float4* bSel    = (float4*)(w + (3 << 20) + (128 << 10)); // 128 KB
  float*  areaSel = (float*)(w + (3 << 20) + (256 << 10));  // 64 KB
  u32*    counts1 = (u32*)(w + (3 << 20) + (320 << 10));    // 64 KB
  u64*    intra1  = (u64*)(w + (3 << 20) + (384 << 10));    // 64 KB
  u32*    rankSel = (u32*)(w + (3 << 20) + (448 << 10));    // 64 KB
  u32*    arriveSel=(u32*)(w + (3 << 20) + (512 << 10));    // 64 KB
  u16*    entries1= (u16*)(w + (3 << 20) + (576 << 10));    // 576 KB
  u32*    selCount= (u32*)(w + (5 << 20));
  u32*    flag    = (u32*)(w + (5 << 20) + 64);
  float4* out     = (float4*)d_out;

  hipMemsetAsync(selCount, 0, 4, stream);
  decode_select_kernel<<<64, 256, 0, stream>>>(
      cls, bbox, anch, boxes_u, keysF, countsF, intraF, rankArrF, arriveF,
      counts1, intra1, rankSel, arriveSel, bSel, areaSel,
      selKeys, selIdx, selCount);
  rank_sel_kernel<<<dim3(SEL_RB, SEL_CB), 256, 0, stream>>>(
      selKeys, selIdx, boxes_u, rankSel, arriveSel, bSel, areaSel, selCount);
  mask1_kernel<<<NP1, 256, 0, stream>>>(bSel, areaSel, counts1, intra1,
                                        entries1);
  resolve1_kernel<<<1, 64, 0, stream>>>(counts1, intra1, entries1, bSel,
                                        selCount, out, flag);
  rank_full_kernel<<<dim3(16, 32), 256, 0, stream>>>(
      keysF, boxes_u, rankArrF, arriveF, bSF, areaSF, flag);
  mask_full_kernel<<<NPAIRS, 256, 0, stream>>>(bSF, areaSF, countsF, intraF,
                                               entriesF, flag);
  resolve_full_kernel<<<1, 64, 0, stream>>>(countsF, intraF, entriesF, bSF,
                                            out, flag);
}